// Round 4
// baseline (279.023 us; speedup 1.0000x reference)
//
#include <hip/hip_runtime.h>

#define B_    16
#define N_    65536
#define C_    256
#define DIN_  16
#define DOUT_ 16

// workspace layout (floats):
//   s      [DIN_][B_][C_]    = 65536 floats  (s[i][b][k])
//   off    [B_][C_][DOUT_]   = 65536 floats  (includes /N and +b1)
//   wd_t   [C_][DIN_*DOUT_]  = 65536 floats  (wd_t[c][i*16+o])
//   c_of_n [N_]              = 65536 ints    (cluster id of source row n)

// ---------------------------------------------------------------------------
// K0: prep. blocks 0..255: transpose w_diag[o][i][c] -> wd_t[c][i*16+o]
//     blocks 256..511: c_of_n[P[j]] = j>>8  AND  zero s (s[k*256+t] = 0)
// ---------------------------------------------------------------------------
__global__ __launch_bounds__(256) void k_prep(
    const float* __restrict__ w_diag, const int* __restrict__ P,
    float* __restrict__ wd_t, int* __restrict__ c_of_n,
    float* __restrict__ s)
{
    int t = threadIdx.x;
    int bid = blockIdx.x;
    if (bid < 256) {
        int o = bid >> 4, i = bid & 15;
        float v = w_diag[bid * C_ + t];       // w_diag[o][i][c], coalesced (t=c)
        wd_t[t * 256 + i * 16 + o] = v;       // scattered 4B write, L2
    } else {
        int k = bid - 256;
        c_of_n[P[k * 256 + t]] = k;
        s[k * 256 + t] = 0.f;                 // zero 65536-float s (poisoned ws)
    }
}

// ---------------------------------------------------------------------------
// K1: sequential cluster sums. block = (b, slab of 2048 rows).
// LDS table [C][17] (pad 17 -> bank spread), LDS atomics, then atomic
// flush to global s (32 contenders per cell).
// ---------------------------------------------------------------------------
__global__ __launch_bounds__(256) void k_sum(
    const float* __restrict__ x, const int* __restrict__ c_of_n,
    float* __restrict__ s)
{
    __shared__ float lds[C_ * 17];
    int t = threadIdx.x;
    int bid = blockIdx.x;
    int b = bid >> 5, slab = bid & 31;
    #pragma unroll
    for (int m = 0; m < 17; ++m) lds[m * 256 + t] = 0.f;
    __syncthreads();

    int lr = t >> 2, q = t & 3;
    const float4* x4 = reinterpret_cast<const float4*>(x);
    int row0 = slab * 2048;
    #pragma unroll 2
    for (int m = 0; m < 32; ++m) {
        int r = row0 + m * 64 + lr;
        float4 v = x4[((size_t)(b * N_ + r)) * 4 + q];   // coalesced 16B/lane
        int c = c_of_n[r];
        float* dst = &lds[c * 17 + q * 4];
        atomicAdd(dst + 0, v.x);
        atomicAdd(dst + 1, v.y);
        atomicAdd(dst + 2, v.z);
        atomicAdd(dst + 3, v.w);
    }
    __syncthreads();
    // thread t flushes cluster t
    #pragma unroll
    for (int i = 0; i < 16; ++i) {
        float v = lds[t * 17 + i];
        unsafeAtomicAdd(&s[i * (B_ * C_) + b * C_ + t], v);  // coalesced atomics
    }
}

// ---------------------------------------------------------------------------
// K2: off[b,c,o] = (1/N) * sum_{i,k} w_off[o,i,c,k] * s[b,k,i] + b1[o]
// grid = C_ * 4 blocks: (c, o-group of 4). thread t owns k = t.
// ---------------------------------------------------------------------------
__global__ __launch_bounds__(256) void k_off(
    const float* __restrict__ w_off, const float* __restrict__ s,
    const float* __restrict__ b1, float* __restrict__ off)
{
    int c  = blockIdx.x >> 2;
    int og = blockIdx.x & 3;
    int t  = threadIdx.x;  // k
    float acc[64];         // [b][o4]
    #pragma unroll
    for (int z = 0; z < 64; ++z) acc[z] = 0.f;

    for (int i = 0; i < DIN_; ++i) {
        float wv[4];
        #pragma unroll
        for (int o4 = 0; o4 < 4; ++o4) {
            int o = og * 4 + o4;
            wv[o4] = w_off[((size_t)((o * DIN_ + i) * C_ + c)) * C_ + t];
        }
        #pragma unroll
        for (int b = 0; b < B_; ++b) {
            float sv = s[i * (B_ * C_) + b * C_ + t];
            #pragma unroll
            for (int o4 = 0; o4 < 4; ++o4) acc[b * 4 + o4] += wv[o4] * sv;
        }
    }

    __shared__ float red[8][256];
    const float invN = 1.0f / (float)N_;
    #pragma unroll
    for (int rd = 0; rd < 8; ++rd) {
        __syncthreads();
        #pragma unroll
        for (int oo = 0; oo < 8; ++oo) red[oo][t] = acc[rd * 8 + oo];
        __syncthreads();
        int grp = t >> 5;
        int seg = t & 31;
        float p = 0.f;
        #pragma unroll
        for (int j = 0; j < 8; ++j) p += red[grp][seg * 8 + j];
        #pragma unroll
        for (int d = 16; d > 0; d >>= 1) p += __shfl_down(p, d, 32);
        if (seg == 0) {
            int outid = rd * 8 + grp;
            int b  = outid >> 2, o4 = outid & 3;
            int o  = og * 4 + o4;
            off[((b << 8) + c) * DOUT_ + o] = p * invN + b1[o];
        }
    }
}

// ---------------------------------------------------------------------------
// K3: sequential apply. block owns 64 contiguous rows n; thread = (row, o-quad).
// grid MUST be N_/64 = 1024 blocks. W_c slice in registers, reused over b.
// out[b,n,o] = sum_i x[b,n,i]*wd[c][i][o] + off[b,c,o]
// ---------------------------------------------------------------------------
__global__ __launch_bounds__(256) void k_apply_seq(
    const float* __restrict__ x, const int* __restrict__ c_of_n,
    const float* __restrict__ wd_t, const float* __restrict__ off,
    float* __restrict__ out)
{
    int t = threadIdx.x;
    int lr = t >> 2, q = t & 3;
    int n = blockIdx.x * 64 + lr;          // blockIdx.x in [0, 1024)
    int c = c_of_n[n];

    const float4* wd4 = reinterpret_cast<const float4*>(wd_t);
    float4 wds[16];   // wd[i][o-quad q] for i=0..15
    #pragma unroll
    for (int i = 0; i < 16; ++i) wds[i] = wd4[c * 64 + i * 4 + q];

    const float4* x4   = reinterpret_cast<const float4*>(x);
    const float4* off4 = reinterpret_cast<const float4*>(off);
    float4* out4       = reinterpret_cast<float4*>(out);

    #pragma unroll 2
    for (int b = 0; b < B_; ++b) {
        size_t rowbase = ((size_t)(b * N_ + n)) * 4;   // float4 units
        float4 x0 = x4[rowbase + 0];
        float4 x1 = x4[rowbase + 1];
        float4 x2 = x4[rowbase + 2];
        float4 x3 = x4[rowbase + 3];
        float4 acc = off4[((size_t)((b << 8) + c)) * 4 + q];
        float xv[16];
        xv[0]=x0.x; xv[1]=x0.y; xv[2]=x0.z; xv[3]=x0.w;
        xv[4]=x1.x; xv[5]=x1.y; xv[6]=x1.z; xv[7]=x1.w;
        xv[8]=x2.x; xv[9]=x2.y; xv[10]=x2.z; xv[11]=x2.w;
        xv[12]=x3.x; xv[13]=x3.y; xv[14]=x3.z; xv[15]=x3.w;
        #pragma unroll
        for (int i = 0; i < 16; ++i) {
            acc.x += xv[i] * wds[i].x;
            acc.y += xv[i] * wds[i].y;
            acc.z += xv[i] * wds[i].z;
            acc.w += xv[i] * wds[i].w;
        }
        out4[rowbase + q] = acc;   // coalesced
    }
}

extern "C" void kernel_launch(void* const* d_in, const int* in_sizes, int n_in,
                              void* d_out, int out_size, void* d_ws, size_t ws_size,
                              hipStream_t stream) {
    const float* x      = (const float*)d_in[0];
    const float* w_diag = (const float*)d_in[1];
    const float* w_off  = (const float*)d_in[2];
    const float* b1     = (const float*)d_in[3];
    const int*   P      = (const int*)d_in[4];
    float* out    = (float*)d_out;
    float* s      = (float*)d_ws;          // 65536 floats
    float* off    = s + 65536;             // 65536 floats
    float* wd_t   = off + 65536;           // 65536 floats
    int*   c_of_n = (int*)(wd_t + 65536);  // 65536 ints

    k_prep<<<512, 256, 0, stream>>>(w_diag, P, wd_t, c_of_n, s);
    k_sum<<<512, 256, 0, stream>>>(x, c_of_n, s);
    k_off<<<C_ * 4, 256, 0, stream>>>(w_off, s, b1, off);
    k_apply_seq<<<N_ / 64, 256, 0, stream>>>(x, c_of_n, wd_t, off, out);
}

// Round 5
// 213.507 us; speedup vs baseline: 1.3069x; 1.3069x over previous
//
#include <hip/hip_runtime.h>

#define B_    16
#define N_    65536
#define C_    256
#define DIN_  16
#define DOUT_ 16

// workspace layout (floats):
//   s      [DIN_][B_][C_]    = 65536 floats  (s[i][b][k])
//   off    [B_][C_][DOUT_]   = 65536 floats  (includes /N and +b1)
//   wd_t   [C_][DIN_*DOUT_]  = 65536 floats  (wd_t[c][i*16+o])
//   c_of_n [N_]              = 65536 ints    (cluster id of source row n)

// ---------------------------------------------------------------------------
// K1: fused prep + cluster sums.
//   blocks [0, 4096): gather-style cluster sum for (b, k) — no atomics.
//   blocks [4096, 4352): transpose w_diag[o][i][c] -> wd_t[c][i*16+o]
//   blocks [4352, 4608): c_of_n[P[j]] = j>>8
// ---------------------------------------------------------------------------
__global__ __launch_bounds__(256) void k_sum_prep(
    const float* __restrict__ x, const float* __restrict__ w_diag,
    const int* __restrict__ P, float* __restrict__ s,
    float* __restrict__ wd_t, int* __restrict__ c_of_n)
{
    int bid = blockIdx.x;
    int t = threadIdx.x;
    if (bid >= B_ * C_) {
        int r = bid - B_ * C_;
        if (r < 256) {
            // r encodes (o,i): w_diag[o][i][c] -> wd_t[c][i*16+o]
            int o = r >> 4, i = r & 15;
            wd_t[t * 256 + i * 16 + o] = w_diag[r * C_ + t];  // coalesced read
        } else {
            int k = r - 256;
            c_of_n[P[k * 256 + t]] = k;
        }
        return;
    }
    int b = bid >> 8;
    int k = bid & (C_ - 1);
    int q  = t & 3;         // which float4 of the 16-float row
    int rg = t >> 2;        // 0..63 row group
    float4 acc = make_float4(0.f, 0.f, 0.f, 0.f);
    const int jbase = k << 8;
    #pragma unroll
    for (int m = 0; m < 4; ++m) {
        int n = P[jbase + rg + 64 * m];
        const float4* row =
            reinterpret_cast<const float4*>(x + ((size_t)(b * N_ + n)) * DIN_);
        float4 v = row[q];
        acc.x += v.x; acc.y += v.y; acc.z += v.z; acc.w += v.w;
    }
    // butterfly reduce over row-groups within the wave (bits 2..5 of lane id)
    #pragma unroll
    for (int mask = 4; mask <= 32; mask <<= 1) {
        acc.x += __shfl_xor(acc.x, mask, 64);
        acc.y += __shfl_xor(acc.y, mask, 64);
        acc.z += __shfl_xor(acc.z, mask, 64);
        acc.w += __shfl_xor(acc.w, mask, 64);
    }
    __shared__ float4 part[4][4];  // [wave][q]
    int lane = t & 63, wave = t >> 6;
    if (lane < 4) part[wave][lane] = acc;  // lane == q for lanes 0..3
    __syncthreads();
    if (t < 16) {
        int qq = t >> 2, comp = t & 3;
        float v = 0.f;
        #pragma unroll
        for (int w = 0; w < 4; ++w) {
            const float* p = reinterpret_cast<const float*>(&part[w][qq]);
            v += p[comp];
        }
        int i = qq * 4 + comp;
        s[i * (B_ * C_) + b * C_ + k] = v;
    }
}

// ---------------------------------------------------------------------------
// K2: off[b,c,o] = (1/N) * sum_{i,k} w_off[o,i,c,k] * s[b,k,i] + b1[o]
// grid = C_ * 4 blocks: (c, o-group of 4). thread t owns k = t.
// ---------------------------------------------------------------------------
__global__ __launch_bounds__(256) void k_off(
    const float* __restrict__ w_off, const float* __restrict__ s,
    const float* __restrict__ b1, float* __restrict__ off)
{
    int c  = blockIdx.x >> 2;
    int og = blockIdx.x & 3;
    int t  = threadIdx.x;  // k
    float acc[64];         // [b][o4]
    #pragma unroll
    for (int z = 0; z < 64; ++z) acc[z] = 0.f;

    for (int i = 0; i < DIN_; ++i) {
        float wv[4];
        #pragma unroll
        for (int o4 = 0; o4 < 4; ++o4) {
            int o = og * 4 + o4;
            wv[o4] = w_off[((size_t)((o * DIN_ + i) * C_ + c)) * C_ + t];
        }
        #pragma unroll
        for (int b = 0; b < B_; ++b) {
            float sv = s[i * (B_ * C_) + b * C_ + t];
            #pragma unroll
            for (int o4 = 0; o4 < 4; ++o4) acc[b * 4 + o4] += wv[o4] * sv;
        }
    }

    __shared__ float red[8][256];
    const float invN = 1.0f / (float)N_;
    #pragma unroll
    for (int rd = 0; rd < 8; ++rd) {
        __syncthreads();
        #pragma unroll
        for (int oo = 0; oo < 8; ++oo) red[oo][t] = acc[rd * 8 + oo];
        __syncthreads();
        int grp = t >> 5;
        int seg = t & 31;
        float p = 0.f;
        #pragma unroll
        for (int j = 0; j < 8; ++j) p += red[grp][seg * 8 + j];
        #pragma unroll
        for (int d = 16; d > 0; d >>= 1) p += __shfl_down(p, d, 32);
        if (seg == 0) {
            int outid = rd * 8 + grp;
            int b  = outid >> 2, o4 = outid & 3;
            int o  = og * 4 + o4;
            off[((b << 8) + c) * DOUT_ + o] = p * invN + b1[o];
        }
    }
}

// ---------------------------------------------------------------------------
// K3: sequential apply. block owns 64 contiguous rows n; thread = (row, o-quad).
// grid = N_/64 = 1024 blocks. W_c slice in registers, reused over b.
// out[b,n,o] = sum_i x[b,n,i]*wd[c][i][o] + off[b,c,o]
// ---------------------------------------------------------------------------
__global__ __launch_bounds__(256) void k_apply_seq(
    const float* __restrict__ x, const int* __restrict__ c_of_n,
    const float* __restrict__ wd_t, const float* __restrict__ off,
    float* __restrict__ out)
{
    int t = threadIdx.x;
    int lr = t >> 2, q = t & 3;
    int n = blockIdx.x * 64 + lr;          // blockIdx.x in [0, 1024)
    int c = c_of_n[n];

    const float4* wd4 = reinterpret_cast<const float4*>(wd_t);
    float4 wds[16];   // wd[i][o-quad q] for i=0..15
    #pragma unroll
    for (int i = 0; i < 16; ++i) wds[i] = wd4[c * 64 + i * 4 + q];

    const float4* x4   = reinterpret_cast<const float4*>(x);
    const float4* off4 = reinterpret_cast<const float4*>(off);
    float4* out4       = reinterpret_cast<float4*>(out);

    #pragma unroll 2
    for (int b = 0; b < B_; ++b) {
        size_t rowbase = ((size_t)(b * N_ + n)) * 4;   // float4 units
        float4 x0 = x4[rowbase + 0];
        float4 x1 = x4[rowbase + 1];
        float4 x2 = x4[rowbase + 2];
        float4 x3 = x4[rowbase + 3];
        float4 acc = off4[((size_t)((b << 8) + c)) * 4 + q];
        float xv[16];
        xv[0]=x0.x; xv[1]=x0.y; xv[2]=x0.z; xv[3]=x0.w;
        xv[4]=x1.x; xv[5]=x1.y; xv[6]=x1.z; xv[7]=x1.w;
        xv[8]=x2.x; xv[9]=x2.y; xv[10]=x2.z; xv[11]=x2.w;
        xv[12]=x3.x; xv[13]=x3.y; xv[14]=x3.z; xv[15]=x3.w;
        #pragma unroll
        for (int i = 0; i < 16; ++i) {
            acc.x += xv[i] * wds[i].x;
            acc.y += xv[i] * wds[i].y;
            acc.z += xv[i] * wds[i].z;
            acc.w += xv[i] * wds[i].w;
        }
        out4[rowbase + q] = acc;   // coalesced
    }
}

extern "C" void kernel_launch(void* const* d_in, const int* in_sizes, int n_in,
                              void* d_out, int out_size, void* d_ws, size_t ws_size,
                              hipStream_t stream) {
    const float* x      = (const float*)d_in[0];
    const float* w_diag = (const float*)d_in[1];
    const float* w_off  = (const float*)d_in[2];
    const float* b1     = (const float*)d_in[3];
    const int*   P      = (const int*)d_in[4];
    float* out    = (float*)d_out;
    float* s      = (float*)d_ws;          // 65536 floats
    float* off    = s + 65536;             // 65536 floats
    float* wd_t   = off + 65536;           // 65536 floats
    int*   c_of_n = (int*)(wd_t + 65536);  // 65536 ints

    k_sum_prep<<<B_ * C_ + 512, 256, 0, stream>>>(x, w_diag, P, s, wd_t, c_of_n);
    k_off<<<C_ * 4, 256, 0, stream>>>(w_off, s, b1, off);
    k_apply_seq<<<N_ / 64, 256, 0, stream>>>(x, c_of_n, wd_t, off, out);
}